// Round 1
// baseline (1068.252 us; speedup 1.0000x reference)
//
#include <hip/hip_runtime.h>
#include <math.h>

#define NN 768
#define KALL 1152     // 192*3 + 144*2 + 288
#define CATD 2112     // 192 + 3*96 + 96 + 1536
#define INF_ 100000.0f
#define PACKN (385 * KALL)

__device__ __forceinline__ float4 ld4(const float* p) { return *(const float4*)p; }

// ---------------- 1. pack combined projection weights (q scaled by 0.25) + wpack ----------------
__global__ __launch_bounds__(256) void pack_kernel(
    const float* wq, const float* bq, const float* wk, const float* bk,
    const float* wv, const float* bv, const float* wqp, const float* bqp,
    const float* wkp, const float* bkp, const float* wvp, const float* bvp,
    const float* wbm, float* Wall, float* ball, float* wpack) {
  int idx = blockIdx.x * 256 + threadIdx.x;
  if (idx >= PACKN + 2048) return;
  if (idx >= PACKN) {
    // wpack[c*16 + h] = wb[c*12 + h], padded to 16 for aligned float4 loads
    int u = idx - PACKN;
    int c = u >> 4, hh = u & 15;
    wpack[u] = (hh < 12) ? wbm[c * 12 + hh] : 0.f;
    return;
  }
  int kk = idx / KALL, u = idx - kk * KALL;
  const float *w, *b; int col, dim; float sc = 1.f;
  if (u < 192)      { w = wq;  b = bq;  col = u;       dim = 192; sc = 0.25f; }
  else if (u < 384) { w = wk;  b = bk;  col = u - 192; dim = 192; }
  else if (u < 576) { w = wv;  b = bv;  col = u - 384; dim = 192; }
  else if (u < 720) { w = wqp; b = bqp; col = u - 576; dim = 144; }
  else if (u < 864) { w = wkp; b = bkp; col = u - 720; dim = 144; }
  else              { w = wvp; b = bvp; col = u - 864; dim = 288; }
  if (kk < 384) Wall[kk * KALL + u] = sc * w[kk * dim + col];
  else          ball[u] = sc * b[col];
}

// ---------------- 2. proj = s @ Wall + ball   [768 x 1152] ----------------
__global__ __launch_bounds__(256) void proj_kernel(const float* s, const float* Wall,
                                                   const float* ball, float* proj) {
  int q0 = blockIdx.x * 32, c0 = blockIdx.y * 64;
  int tid = threadIdx.x;
  int qa = q0 + (tid >> 4) * 2, qb = qa + 1;
  int c = c0 + (tid & 15) * 4;
  const float* sa = s + qa * 384;
  const float* sb = s + qb * 384;
  const float* wp = Wall + c;
  float4 acc0 = {0, 0, 0, 0}, acc1 = {0, 0, 0, 0};
#pragma unroll 4
  for (int k = 0; k < 384; k++) {
    float4 w4 = ld4(wp + k * KALL);
    float a0 = sa[k], a1 = sb[k];
    acc0.x += a0 * w4.x; acc0.y += a0 * w4.y; acc0.z += a0 * w4.z; acc0.w += a0 * w4.w;
    acc1.x += a1 * w4.x; acc1.y += a1 * w4.y; acc1.z += a1 * w4.z; acc1.w += a1 * w4.w;
  }
  float4 b4 = ld4(ball + c);
  acc0.x += b4.x; acc0.y += b4.y; acc0.z += b4.z; acc0.w += b4.w;
  acc1.x += b4.x; acc1.y += b4.y; acc1.z += b4.z; acc1.w += b4.w;
  *(float4*)(proj + (size_t)qa * KALL + c) = acc0;
  *(float4*)(proj + (size_t)qb * KALL + c) = acc1;
}

// ---------------- 3. rigid-transform points + q2/k2 ----------------
__global__ __launch_bounds__(256) void points_kernel(const float* proj, const float* rot,
                                                     const float* trans, float* qpts, float* kpts,
                                                     float* vpts, float* q2, float* k2) {
  int n = blockIdx.x, tid = threadIdx.x;
  __shared__ float sq[12], sk[12];
  if (tid < 12) { sq[tid] = 0.f; sk[tid] = 0.f; }
  __syncthreads();
  if (tid < 192) {
    const float* R = rot + n * 9;
    const float* T = trans + n * 3;
    const float* pr = proj + (size_t)n * KALL;
    int base, P; float* outp; int h; bool isq = false, isk = false;
    if (tid < 48)      { h = tid >> 2; int p = tid & 3; base = 576 + h * 12; P = 4;
                         outp = qpts + n * 144 + h * 12 + p * 3; base += p; isq = true; }
    else if (tid < 96) { int i = tid - 48; h = i >> 2; int p = i & 3; base = 720 + h * 12; P = 4;
                         outp = kpts + n * 144 + h * 12 + p * 3; base += p; isk = true; }
    else               { int i = tid - 96; h = i >> 3; int p = i & 7; base = 864 + h * 24; P = 8;
                         outp = vpts + n * 288 + h * 24 + p * 3; base += p; }
    float l0 = pr[base], l1 = pr[base + P], l2 = pr[base + 2 * P];
    float g0 = R[0] * l0 + R[1] * l1 + R[2] * l2 + T[0];
    float g1 = R[3] * l0 + R[4] * l1 + R[5] * l2 + T[1];
    float g2 = R[6] * l0 + R[7] * l1 + R[8] * l2 + T[2];
    outp[0] = g0; outp[1] = g1; outp[2] = g2;
    float ns = g0 * g0 + g1 * g1 + g2 * g2;
    if (isq) atomicAdd(&sq[h], ns);
    else if (isk) atomicAdd(&sk[h], ns);
  }
  __syncthreads();
  if (tid < 12) { q2[n * 12 + tid] = sq[tid]; k2[n * 12 + tid] = sk[tid]; }
}

// ---------------- 4. bias[q][h][k] = z[q,k,:] . w_b[:,h] + b_b[h] ----------------
// LDS-free: weights from wpack (wave-uniform float4 loads -> s_load/L1 broadcast),
// each thread owns 3 k-rows so 12 weight loads amortize over 144 FMAs.
__global__ __launch_bounds__(256) void bias_kernel(const float* __restrict__ z,
                                                   const float* __restrict__ wpack,
                                                   const float* __restrict__ bb,
                                                   float* __restrict__ abuf) {
  int q = blockIdx.x;
  int kl = threadIdx.x;  // k = kl, kl+256, kl+512
  const float* zp0 = z + ((size_t)q * NN + kl) * 128;
  float acc0[12], acc1[12], acc2[12];
#pragma unroll
  for (int h = 0; h < 12; h++) { acc0[h] = 0.f; acc1[h] = 0.f; acc2[h] = 0.f; }
  for (int c = 0; c < 128; c += 4) {
    float4 z0 = ld4(zp0 + c);
    float4 z1 = ld4(zp0 + 256 * 128 + c);
    float4 z2 = ld4(zp0 + 512 * 128 + c);
    const float zc0[4] = {z0.x, z0.y, z0.z, z0.w};
    const float zc1[4] = {z1.x, z1.y, z1.z, z1.w};
    const float zc2[4] = {z2.x, z2.y, z2.z, z2.w};
    const float* wp = wpack + c * 16;
#pragma unroll
    for (int cc = 0; cc < 4; cc++) {
      float4 wA = ld4(wp + cc * 16);
      float4 wB = ld4(wp + cc * 16 + 4);
      float4 wC = ld4(wp + cc * 16 + 8);
      float v0 = zc0[cc], v1 = zc1[cc], v2 = zc2[cc];
      acc0[0] += v0 * wA.x; acc0[1] += v0 * wA.y; acc0[2] += v0 * wA.z; acc0[3] += v0 * wA.w;
      acc0[4] += v0 * wB.x; acc0[5] += v0 * wB.y; acc0[6] += v0 * wB.z; acc0[7] += v0 * wB.w;
      acc0[8] += v0 * wC.x; acc0[9] += v0 * wC.y; acc0[10] += v0 * wC.z; acc0[11] += v0 * wC.w;
      acc1[0] += v1 * wA.x; acc1[1] += v1 * wA.y; acc1[2] += v1 * wA.z; acc1[3] += v1 * wA.w;
      acc1[4] += v1 * wB.x; acc1[5] += v1 * wB.y; acc1[6] += v1 * wB.z; acc1[7] += v1 * wB.w;
      acc1[8] += v1 * wC.x; acc1[9] += v1 * wC.y; acc1[10] += v1 * wC.z; acc1[11] += v1 * wC.w;
      acc2[0] += v2 * wA.x; acc2[1] += v2 * wA.y; acc2[2] += v2 * wA.z; acc2[3] += v2 * wA.w;
      acc2[4] += v2 * wB.x; acc2[5] += v2 * wB.y; acc2[6] += v2 * wB.z; acc2[7] += v2 * wB.w;
      acc2[8] += v2 * wC.x; acc2[9] += v2 * wC.y; acc2[10] += v2 * wC.z; acc2[11] += v2 * wC.w;
    }
  }
#pragma unroll
  for (int h = 0; h < 12; h++) {
    float b = bb[h];
    float* ap = abuf + ((size_t)q * 12 + h) * NN + kl;
    ap[0] = acc0[h] + b;
    ap[256] = acc1[h] + b;
    ap[512] = acc2[h] + b;
  }
}

// ---------------- 5. logits + softmax (in-place over abuf) ----------------
__global__ __launch_bounds__(256) void softmax_kernel(const float* proj, const float* qpts,
                                                      const float* kpts, const float* q2,
                                                      const float* k2, const float* mask,
                                                      const float* hw, float* abuf) {
  int q0 = blockIdx.x * 8, h = blockIdx.y;
  int tid = threadIdx.x;
  __shared__ float qw[8][16], qp[8][12], q2s[8], mq[8], red[4][8], row[8], pws;
  if (tid < 128) qw[tid >> 4][tid & 15] = proj[(size_t)(q0 + (tid >> 4)) * KALL + h * 16 + (tid & 15)];
  else if (tid < 224) { int i = tid - 128; qp[i / 12][i % 12] = qpts[(q0 + i / 12) * 144 + h * 12 + i % 12]; }
  else if (tid < 232) q2s[tid - 224] = q2[(q0 + tid - 224) * 12 + h];
  else if (tid < 240) mq[tid - 232] = mask[q0 + tid - 232];
  else if (tid == 240) {
    float x = hw[h];
    pws = 0.23570226039551584f * (fmaxf(x, 0.f) + log1pf(__expf(-fabsf(x))));
  }
  __syncthreads();

  float L[3][8];
#pragma unroll
  for (int i = 0; i < 3; i++) {
    int kk = i * 256 + tid;
    float kw[16], kp[12];
    const float* kwp = proj + (size_t)kk * KALL + 192 + h * 16;
    *(float4*)(kw) = ld4(kwp); *(float4*)(kw + 4) = ld4(kwp + 4);
    *(float4*)(kw + 8) = ld4(kwp + 8); *(float4*)(kw + 12) = ld4(kwp + 12);
    const float* kpp = kpts + (size_t)kk * 144 + h * 12;
    *(float4*)(kp) = ld4(kpp); *(float4*)(kp + 4) = ld4(kpp + 4); *(float4*)(kp + 8) = ld4(kpp + 8);
    float k2v = k2[kk * 12 + h];
    float mk = mask[kk];
#pragma unroll
    for (int q = 0; q < 8; q++) {
      float4 qa = *(const float4*)&qw[q][0];
      float4 qb = *(const float4*)&qw[q][4];
      float4 qc = *(const float4*)&qw[q][8];
      float4 qd = *(const float4*)&qw[q][12];
      float4 pa = *(const float4*)&qp[q][0];
      float4 pb = *(const float4*)&qp[q][4];
      float4 pc = *(const float4*)&qp[q][8];
      float d = qa.x * kw[0] + qa.y * kw[1] + qa.z * kw[2] + qa.w * kw[3]
              + qb.x * kw[4] + qb.y * kw[5] + qb.z * kw[6] + qb.w * kw[7]
              + qc.x * kw[8] + qc.y * kw[9] + qc.z * kw[10] + qc.w * kw[11]
              + qd.x * kw[12] + qd.y * kw[13] + qd.z * kw[14] + qd.w * kw[15];
      float dp = pa.x * kp[0] + pa.y * kp[1] + pa.z * kp[2] + pa.w * kp[3]
               + pb.x * kp[4] + pb.y * kp[5] + pb.z * kp[6] + pb.w * kp[7]
               + pc.x * kp[8] + pc.y * kp[9] + pc.z * kp[10] + pc.w * kp[11];
      float bias = abuf[((size_t)(q0 + q) * 12 + h) * NN + kk];
      float val = bias + d - 0.5f * pws * (q2s[q] + k2v - 2.f * dp) + INF_ * (mq[q] * mk - 1.f);
      L[i][q] = val * 0.5773502691896258f;
    }
  }
  float m[8];
#pragma unroll
  for (int q = 0; q < 8; q++) m[q] = fmaxf(fmaxf(L[0][q], L[1][q]), L[2][q]);
#pragma unroll
  for (int d = 1; d < 64; d <<= 1)
#pragma unroll
    for (int q = 0; q < 8; q++) m[q] = fmaxf(m[q], __shfl_xor(m[q], d, 64));
  int wv = tid >> 6;
  if ((tid & 63) == 0)
    for (int q = 0; q < 8; q++) red[wv][q] = m[q];
  __syncthreads();
  if (tid < 8) row[tid] = fmaxf(fmaxf(red[0][tid], red[1][tid]), fmaxf(red[2][tid], red[3][tid]));
  __syncthreads();
  float sm[8];
#pragma unroll
  for (int q = 0; q < 8; q++) {
    float mm = row[q];
    L[0][q] = __expf(L[0][q] - mm);
    L[1][q] = __expf(L[1][q] - mm);
    L[2][q] = __expf(L[2][q] - mm);
    sm[q] = L[0][q] + L[1][q] + L[2][q];
  }
#pragma unroll
  for (int d = 1; d < 64; d <<= 1)
#pragma unroll
    for (int q = 0; q < 8; q++) sm[q] += __shfl_xor(sm[q], d, 64);
  if ((tid & 63) == 0)
    for (int q = 0; q < 8; q++) red[wv][q] = sm[q];
  __syncthreads();
  if (tid < 8) row[tid] = 1.f / (red[0][tid] + red[1][tid] + red[2][tid] + red[3][tid]);
  __syncthreads();
#pragma unroll
  for (int q = 0; q < 8; q++) {
    float r = row[q];
    float* ap = abuf + ((size_t)(q0 + q) * 12 + h) * NN + tid;
    ap[0] = L[0][q] * r; ap[256] = L[1][q] * r; ap[512] = L[2][q] * r;
  }
}

// ---------------- 6. o_pair[q][h][c] = sum_k a[q,h,k] z[q,k,c]  -> cat cols 576.. ----------------
__global__ __launch_bounds__(256) void opair_kernel(const float* z, const float* abuf, float* cat) {
  int q = blockIdx.x, tid = threadIdx.x;
  int c = tid & 127, h0 = tid >> 7;
  const float* zp = z + (size_t)q * NN * 128 + c;
  const float* ap = abuf + (size_t)q * 12 * NN;
  float acc[6] = {0, 0, 0, 0, 0, 0};
  for (int k4 = 0; k4 < NN; k4 += 4) {
    float4 av[6];
#pragma unroll
    for (int j = 0; j < 6; j++) av[j] = ld4(ap + (h0 + 2 * j) * NN + k4);
#pragma unroll
    for (int kk = 0; kk < 4; kk++) {
      float zv = zp[(size_t)(k4 + kk) * 128];
      const float* avf;
#pragma unroll
      for (int j = 0; j < 6; j++) {
        avf = (const float*)&av[j];
        acc[j] += zv * avf[kk];
      }
    }
  }
#pragma unroll
  for (int j = 0; j < 6; j++)
    cat[(size_t)q * CATD + 576 + (h0 + 2 * j) * 128 + c] = acc[j];
}

// ---------------- 7a. o + o_pt partials over k-chunks (split-K for occupancy) ----------------
// grid (12, 24, 4): each block does 192 k. pov layout [kz][q][h][40]: o(16) then pt(24).
__global__ __launch_bounds__(256) void ovpart_kernel(const float* proj, const float* vpts,
                                                     const float* abuf, float* pov) {
  int h = blockIdx.x, q0 = blockIdx.y * 32, kz = blockIdx.z;
  int tid = threadIdx.x;
  int qg = tid >> 3, jb = tid & 7;
  int q = q0 + qg;
  const float* ap = abuf + ((size_t)q * 12 + h) * NN + kz * 192;
  const float* vp = proj + (size_t)(kz * 192) * KALL + 384 + h * 16;   // + k*KALL
  const float* vpp = vpts + (size_t)(kz * 192) * 288 + h * 24;         // + k*288
  float acc[5] = {0, 0, 0, 0, 0};
  for (int k = 0; k < 192; k += 4) {
    float4 a4 = ld4(ap + k);
    const float af[4] = {a4.x, a4.y, a4.z, a4.w};
#pragma unroll
    for (int kk = 0; kk < 4; kk++) {
      float av = af[kk];
      size_t kr = k + kk;
      acc[0] += av * vp[kr * KALL + jb];
      acc[1] += av * vp[kr * KALL + jb + 8];
      acc[2] += av * vpp[kr * 288 + jb];
      acc[3] += av * vpp[kr * 288 + jb + 8];
      acc[4] += av * vpp[kr * 288 + jb + 16];
    }
  }
  float* o = pov + (((size_t)kz * 768 + q) * 12 + h) * 40;
  o[jb] = acc[0]; o[jb + 8] = acc[1];
  o[16 + jb] = acc[2]; o[16 + jb + 8] = acc[3]; o[16 + jb + 16] = acc[4];
}

// ---------------- 7b. reduce partials; o -> cat; inverse rigid + norm for o_pt ----------------
__global__ __launch_bounds__(256) void ovred_kernel(const float* pov, const float* rot,
                                                    const float* trans, float* cat) {
  int q = blockIdx.x, tid = threadIdx.x;
  const float* pq = pov + (size_t)q * 480;  // + kz*768*480
  if (tid < 96) {
    // pt: h = tid>>3, p = tid&7
    int h = tid >> 3, p = tid & 7;
    float x = 0.f, y = 0.f, zz = 0.f;
#pragma unroll
    for (int j = 0; j < 4; j++) {
      const float* b = pq + (size_t)j * 768 * 480 + h * 40 + 16 + p * 3;
      x += b[0]; y += b[1]; zz += b[2];
    }
    const float* R = rot + q * 9;
    const float* T = trans + q * 3;
    float dx = x - T[0], dy = y - T[1], dz = zz - T[2];
    float lx = R[0] * dx + R[3] * dy + R[6] * dz;  // R^T
    float ly = R[1] * dx + R[4] * dy + R[7] * dz;
    float lz = R[2] * dx + R[5] * dy + R[8] * dz;
    float nrm = sqrtf(lx * lx + ly * ly + lz * lz + 1e-8f);
    int hp = h * 8 + p;
    float* co = cat + (size_t)q * CATD;
    co[192 + hp] = lx; co[288 + hp] = ly; co[384 + hp] = lz; co[480 + hp] = nrm;
  } else {
    // o: 192 items
    int i = tid - 96;  // [0,160) covers? no: 256-96=160 < 192 -> handle 192 via i and i+160? keep simple below
    // Use i in [0,192): threads 96..255 = 160 threads; remaining 32 handled by first 32 threads? 
    // Simpler: all threads 96..255 do one item; threads 96..127 also do a second item.
    int h = i >> 4, c = i & 15;
    float s = 0.f;
#pragma unroll
    for (int j = 0; j < 4; j++) s += pq[(size_t)j * 768 * 480 + h * 40 + c];
    cat[(size_t)q * CATD + h * 16 + c] = s;
    if (i < 32) {
      int i2 = i + 160;
      int h2 = i2 >> 4, c2 = i2 & 15;
      float s2 = 0.f;
#pragma unroll
      for (int j = 0; j < 4; j++) s2 += pq[(size_t)j * 768 * 480 + h2 * 40 + c2];
      cat[(size_t)q * CATD + h2 * 16 + c2] = s2;
    }
  }
}

// ---------------- 8a. out partials: split-K GEMM  cat[768x2112] @ wo[2112x384] ----------------
__global__ __launch_bounds__(256) void out_part_kernel(const float* cat, const float* wo,
                                                       float* part) {
  int q0 = blockIdx.x * 16, c0 = blockIdx.y * 64, k0 = blockIdx.z * 264;
  int tid = threadIdx.x;
  int q = q0 + (tid >> 4);
  int c = c0 + (tid & 15) * 4;
  const float* cp = cat + (size_t)q * CATD + k0;
  const float* wp = wo + (size_t)k0 * 384 + c;
  float4 acc = {0, 0, 0, 0};
#pragma unroll 8
  for (int k = 0; k < 264; k++) {
    float a = cp[k];
    float4 w4 = ld4(wp + (size_t)k * 384);
    acc.x += a * w4.x; acc.y += a * w4.y; acc.z += a * w4.z; acc.w += a * w4.w;
  }
  *(float4*)(part + ((size_t)blockIdx.z * 768 + q) * 384 + c) = acc;
}

// ---------------- 8b. out = sum_j part[j] + b_o ----------------
__global__ __launch_bounds__(256) void out_reduce_kernel(const float* part, const float* bo,
                                                         float* out) {
  int idx = blockIdx.x * 256 + threadIdx.x;
  int q = idx / 96, cg = idx - q * 96;
  int c = cg * 4;
  float4 acc = ld4(bo + c);
#pragma unroll
  for (int j = 0; j < 8; j++) {
    float4 p = ld4(part + ((size_t)j * 768 + q) * 384 + c);
    acc.x += p.x; acc.y += p.y; acc.z += p.z; acc.w += p.w;
  }
  *(float4*)(out + (size_t)q * 384 + c) = acc;
}

extern "C" void kernel_launch(void* const* d_in, const int* in_sizes, int n_in,
                              void* d_out, int out_size, void* d_ws, size_t ws_size,
                              hipStream_t stream) {
  const float* s     = (const float*)d_in[0];
  const float* z     = (const float*)d_in[1];
  const float* rot   = (const float*)d_in[2];
  const float* trans = (const float*)d_in[3];
  const float* mask  = (const float*)d_in[4];
  const float* wq    = (const float*)d_in[5];
  const float* bq    = (const float*)d_in[6];
  const float* wk    = (const float*)d_in[7];
  const float* bk    = (const float*)d_in[8];
  const float* wv    = (const float*)d_in[9];
  const float* bv    = (const float*)d_in[10];
  const float* wqp   = (const float*)d_in[11];
  const float* bqp   = (const float*)d_in[12];
  const float* wkp   = (const float*)d_in[13];
  const float* bkp   = (const float*)d_in[14];
  const float* wvp   = (const float*)d_in[15];
  const float* bvp   = (const float*)d_in[16];
  const float* wb    = (const float*)d_in[17];
  const float* bb    = (const float*)d_in[18];
  const float* hw    = (const float*)d_in[19];
  const float* wo    = (const float*)d_in[20];
  const float* bo    = (const float*)d_in[21];
  float* out = (float*)d_out;

  float* ws = (float*)d_ws;
  float* proj  = ws;                       // 768*1152
  float* Wall  = proj + 884736;            // 384*1152
  float* ball  = Wall + 442368;            // 1152
  float* qpts  = ball + 1152;              // 768*144
  float* kpts  = qpts + 110592;            // 768*144
  float* vpts  = kpts + 110592;            // 768*288
  float* q2    = vpts + 221184;            // 768*12
  float* k2    = q2 + 9216;                // 768*12
  float* abuf  = k2 + 9216;                // 768*12*768
  float* cat   = abuf + 7077888;           // 768*2112
  float* part  = cat + 1622016;            // 8*768*384
  float* wpack = part + 2359296;           // 128*16
  float* pov   = wpack + 2048;             // 4*768*12*40

  pack_kernel<<<dim3((PACKN + 2048 + 255) / 256), 256, 0, stream>>>(
      wq, bq, wk, bk, wv, bv, wqp, bqp, wkp, bkp, wvp, bvp, wb, Wall, ball, wpack);
  proj_kernel<<<dim3(24, 18), 256, 0, stream>>>(s, Wall, ball, proj);
  points_kernel<<<dim3(768), 256, 0, stream>>>(proj, rot, trans, qpts, kpts, vpts, q2, k2);
  bias_kernel<<<dim3(768), 256, 0, stream>>>(z, wpack, bb, abuf);
  softmax_kernel<<<dim3(96, 12), 256, 0, stream>>>(proj, qpts, kpts, q2, k2, mask, hw, abuf);
  opair_kernel<<<dim3(768), 256, 0, stream>>>(z, abuf, cat);
  ovpart_kernel<<<dim3(12, 24, 4), 256, 0, stream>>>(proj, vpts, abuf, pov);
  ovred_kernel<<<dim3(768), 256, 0, stream>>>(pov, rot, trans, cat);
  out_part_kernel<<<dim3(48, 6, 8), 256, 0, stream>>>(cat, wo, part);
  out_reduce_kernel<<<dim3(288), 256, 0, stream>>>(part, bo, out);
}

// Round 2
// 873.298 us; speedup vs baseline: 1.2232x; 1.2232x over previous
//
#include <hip/hip_runtime.h>
#include <math.h>

#define NN 768
#define KALL 1152     // 192*3 + 144*2 + 288
#define CATD 2112     // 192 + 3*96 + 96 + 1536
#define INF_ 100000.0f
#define PACKN (385 * KALL)

__device__ __forceinline__ float4 ld4(const float* p) { return *(const float4*)p; }

// ---------------- 1. pack combined projection weights (q scaled by 0.25) + wtr ----------------
__global__ __launch_bounds__(256) void pack_kernel(
    const float* wq, const float* bq, const float* wk, const float* bk,
    const float* wv, const float* bv, const float* wqp, const float* bqp,
    const float* wkp, const float* bkp, const float* wvp, const float* bvp,
    const float* wbm, float* Wall, float* ball, float* wtr) {
  int idx = blockIdx.x * 256 + threadIdx.x;
  if (idx >= PACKN + 1536) return;
  if (idx >= PACKN) {
    // wtr[h*128 + c] = wb[c*12 + h]  (transposed pair-bias weights)
    int u = idx - PACKN;
    int h = u >> 7, c = u & 127;
    wtr[u] = wbm[c * 12 + h];
    return;
  }
  int kk = idx / KALL, u = idx - kk * KALL;
  const float *w, *b; int col, dim; float sc = 1.f;
  if (u < 192)      { w = wq;  b = bq;  col = u;       dim = 192; sc = 0.25f; }
  else if (u < 384) { w = wk;  b = bk;  col = u - 192; dim = 192; }
  else if (u < 576) { w = wv;  b = bv;  col = u - 384; dim = 192; }
  else if (u < 720) { w = wqp; b = bqp; col = u - 576; dim = 144; }
  else if (u < 864) { w = wkp; b = bkp; col = u - 720; dim = 144; }
  else              { w = wvp; b = bvp; col = u - 864; dim = 288; }
  if (kk < 384) Wall[kk * KALL + u] = sc * w[kk * dim + col];
  else          ball[u] = sc * b[col];
}

// ---------------- 2. proj = s @ Wall + ball   [768 x 1152] ----------------
__global__ __launch_bounds__(256) void proj_kernel(const float* s, const float* Wall,
                                                   const float* ball, float* proj) {
  int q0 = blockIdx.x * 32, c0 = blockIdx.y * 64;
  int tid = threadIdx.x;
  int qa = q0 + (tid >> 4) * 2, qb = qa + 1;
  int c = c0 + (tid & 15) * 4;
  const float* sa = s + qa * 384;
  const float* sb = s + qb * 384;
  const float* wp = Wall + c;
  float4 acc0 = {0, 0, 0, 0}, acc1 = {0, 0, 0, 0};
#pragma unroll 4
  for (int k = 0; k < 384; k++) {
    float4 w4 = ld4(wp + k * KALL);
    float a0 = sa[k], a1 = sb[k];
    acc0.x += a0 * w4.x; acc0.y += a0 * w4.y; acc0.z += a0 * w4.z; acc0.w += a0 * w4.w;
    acc1.x += a1 * w4.x; acc1.y += a1 * w4.y; acc1.z += a1 * w4.z; acc1.w += a1 * w4.w;
  }
  float4 b4 = ld4(ball + c);
  acc0.x += b4.x; acc0.y += b4.y; acc0.z += b4.z; acc0.w += b4.w;
  acc1.x += b4.x; acc1.y += b4.y; acc1.z += b4.z; acc1.w += b4.w;
  *(float4*)(proj + (size_t)qa * KALL + c) = acc0;
  *(float4*)(proj + (size_t)qb * KALL + c) = acc1;
}

// ---------------- 3. rigid-transform points + q2/k2 ----------------
__global__ __launch_bounds__(256) void points_kernel(const float* proj, const float* rot,
                                                     const float* trans, float* qpts, float* kpts,
                                                     float* vpts, float* q2, float* k2) {
  int n = blockIdx.x, tid = threadIdx.x;
  __shared__ float sq[12], sk[12];
  if (tid < 12) { sq[tid] = 0.f; sk[tid] = 0.f; }
  __syncthreads();
  if (tid < 192) {
    const float* R = rot + n * 9;
    const float* T = trans + n * 3;
    const float* pr = proj + (size_t)n * KALL;
    int base, P; float* outp; int h; bool isq = false, isk = false;
    if (tid < 48)      { h = tid >> 2; int p = tid & 3; base = 576 + h * 12; P = 4;
                         outp = qpts + n * 144 + h * 12 + p * 3; base += p; isq = true; }
    else if (tid < 96) { int i = tid - 48; h = i >> 2; int p = i & 3; base = 720 + h * 12; P = 4;
                         outp = kpts + n * 144 + h * 12 + p * 3; base += p; isk = true; }
    else               { int i = tid - 96; h = i >> 3; int p = i & 7; base = 864 + h * 24; P = 8;
                         outp = vpts + n * 288 + h * 24 + p * 3; base += p; }
    float l0 = pr[base], l1 = pr[base + P], l2 = pr[base + 2 * P];
    float g0 = R[0] * l0 + R[1] * l1 + R[2] * l2 + T[0];
    float g1 = R[3] * l0 + R[4] * l1 + R[5] * l2 + T[1];
    float g2 = R[6] * l0 + R[7] * l1 + R[8] * l2 + T[2];
    outp[0] = g0; outp[1] = g1; outp[2] = g2;
    float ns = g0 * g0 + g1 * g1 + g2 * g2;
    if (isq) atomicAdd(&sq[h], ns);
    else if (isk) atomicAdd(&sk[h], ns);
  }
  __syncthreads();
  if (tid < 12) { q2[n * 12 + tid] = sq[tid]; k2[n * 12 + tid] = sk[tid]; }
}

// ---------------- 4. bias[q][h][k] = z[q,k,:] . w_b[:,h] + b_b[h] ----------------
// Streaming z: 32-lane group owns a k-row, lane owns a c-quad; wave reads rows (k,k+1)
// as one contiguous 1KB burst (zero over-fetch). Weights k-invariant in VGPRs.
// Reduce: DPP-cheap xor1+xor2 -> 8 quad-partials per row -> LDS -> coalesced dump.
__global__ __launch_bounds__(256) void bias_kernel(const float* __restrict__ z,
                                                   const float* __restrict__ wtr,
                                                   const float* __restrict__ bb,
                                                   float* __restrict__ abuf) {
  int q = blockIdx.x, k0 = blockIdx.y * 96;
  int tid = threadIdx.x;
  int lane = tid & 63;
  int wv = tid >> 6;          // wave 0..3
  int grp = lane >> 5;        // row parity within wave
  int cl = lane & 31;         // c-quad index
  __shared__ float lsm[96 * 100];  // [row][quad*12 + sub*4 ...], padded stride 100

  // per-lane weights: w4[h] = wtr[h*128 + cl*4 .. +3]
  float4 w4[12];
#pragma unroll
  for (int h = 0; h < 12; h++) w4[h] = ld4(wtr + h * 128 + cl * 4);

  const float* zq = z + ((size_t)q * NN + k0) * 128;
  int rbase = wv * 24;
  int quad = cl >> 2, sub = cl & 3;
#pragma unroll 2
  for (int it = 0; it < 12; it++) {
    int rloc = rbase + it * 2 + grp;  // 0..95
    float4 z4 = ld4(zq + (size_t)rloc * 128 + cl * 4);
    float a[12];
#pragma unroll
    for (int h = 0; h < 12; h++)
      a[h] = z4.x * w4[h].x + z4.y * w4[h].y + z4.z * w4[h].z + z4.w * w4[h].w;
#pragma unroll
    for (int h = 0; h < 12; h++) {
      a[h] += __shfl_xor(a[h], 1, 64);
      a[h] += __shfl_xor(a[h], 2, 64);
    }
    // quad-sum now in all 4 lanes of each quad; lanes sub=0,1,2 write h-groups 0..3,4..7,8..11
    bool s1 = (sub == 1), s2 = (sub == 2);
    float vx = s1 ? a[4] : (s2 ? a[8]  : a[0]);
    float vy = s1 ? a[5] : (s2 ? a[9]  : a[1]);
    float vz = s1 ? a[6] : (s2 ? a[10] : a[2]);
    float vw = s1 ? a[7] : (s2 ? a[11] : a[3]);
    if (sub < 3) {
      float* p = lsm + rloc * 100 + quad * 12 + sub * 4;
      *(float4*)p = make_float4(vx, vy, vz, vw);
    }
  }
  __syncthreads();
  // dump: 96 rows x 12 h; sum 8 quad partials; coalesced global write
  for (int i = tid; i < 96 * 12; i += 256) {
    int h = i / 96, k = i - h * 96;
    const float* p = lsm + k * 100 + h;
    float ssum = bb[h];
#pragma unroll
    for (int g = 0; g < 8; g++) ssum += p[g * 12];
    abuf[((size_t)q * 12 + h) * NN + k0 + k] = ssum;
  }
}

// ---------------- 5. logits + softmax (in-place over abuf) ----------------
__global__ __launch_bounds__(256) void softmax_kernel(const float* proj, const float* qpts,
                                                      const float* kpts, const float* q2,
                                                      const float* k2, const float* mask,
                                                      const float* hw, float* abuf) {
  int q0 = blockIdx.x * 8, h = blockIdx.y;
  int tid = threadIdx.x;
  __shared__ float qw[8][16], qp[8][12], q2s[8], mq[8], red[4][8], row[8], pws;
  if (tid < 128) qw[tid >> 4][tid & 15] = proj[(size_t)(q0 + (tid >> 4)) * KALL + h * 16 + (tid & 15)];
  else if (tid < 224) { int i = tid - 128; qp[i / 12][i % 12] = qpts[(q0 + i / 12) * 144 + h * 12 + i % 12]; }
  else if (tid < 232) q2s[tid - 224] = q2[(q0 + tid - 224) * 12 + h];
  else if (tid < 240) mq[tid - 232] = mask[q0 + tid - 232];
  else if (tid == 240) {
    float x = hw[h];
    pws = 0.23570226039551584f * (fmaxf(x, 0.f) + log1pf(__expf(-fabsf(x))));
  }
  __syncthreads();

  float L[3][8];
#pragma unroll
  for (int i = 0; i < 3; i++) {
    int kk = i * 256 + tid;
    float kw[16], kp[12];
    const float* kwp = proj + (size_t)kk * KALL + 192 + h * 16;
    *(float4*)(kw) = ld4(kwp); *(float4*)(kw + 4) = ld4(kwp + 4);
    *(float4*)(kw + 8) = ld4(kwp + 8); *(float4*)(kw + 12) = ld4(kwp + 12);
    const float* kpp = kpts + (size_t)kk * 144 + h * 12;
    *(float4*)(kp) = ld4(kpp); *(float4*)(kp + 4) = ld4(kpp + 4); *(float4*)(kp + 8) = ld4(kpp + 8);
    float k2v = k2[kk * 12 + h];
    float mk = mask[kk];
#pragma unroll
    for (int q = 0; q < 8; q++) {
      float4 qa = *(const float4*)&qw[q][0];
      float4 qb = *(const float4*)&qw[q][4];
      float4 qc = *(const float4*)&qw[q][8];
      float4 qd = *(const float4*)&qw[q][12];
      float4 pa = *(const float4*)&qp[q][0];
      float4 pb = *(const float4*)&qp[q][4];
      float4 pc = *(const float4*)&qp[q][8];
      float d = qa.x * kw[0] + qa.y * kw[1] + qa.z * kw[2] + qa.w * kw[3]
              + qb.x * kw[4] + qb.y * kw[5] + qb.z * kw[6] + qb.w * kw[7]
              + qc.x * kw[8] + qc.y * kw[9] + qc.z * kw[10] + qc.w * kw[11]
              + qd.x * kw[12] + qd.y * kw[13] + qd.z * kw[14] + qd.w * kw[15];
      float dp = pa.x * kp[0] + pa.y * kp[1] + pa.z * kp[2] + pa.w * kp[3]
               + pb.x * kp[4] + pb.y * kp[5] + pb.z * kp[6] + pb.w * kp[7]
               + pc.x * kp[8] + pc.y * kp[9] + pc.z * kp[10] + pc.w * kp[11];
      float bias = abuf[((size_t)(q0 + q) * 12 + h) * NN + kk];
      float val = bias + d - 0.5f * pws * (q2s[q] + k2v - 2.f * dp) + INF_ * (mq[q] * mk - 1.f);
      L[i][q] = val * 0.5773502691896258f;
    }
  }
  float m[8];
#pragma unroll
  for (int q = 0; q < 8; q++) m[q] = fmaxf(fmaxf(L[0][q], L[1][q]), L[2][q]);
#pragma unroll
  for (int d = 1; d < 64; d <<= 1)
#pragma unroll
    for (int q = 0; q < 8; q++) m[q] = fmaxf(m[q], __shfl_xor(m[q], d, 64));
  int wv = tid >> 6;
  if ((tid & 63) == 0)
    for (int q = 0; q < 8; q++) red[wv][q] = m[q];
  __syncthreads();
  if (tid < 8) row[tid] = fmaxf(fmaxf(red[0][tid], red[1][tid]), fmaxf(red[2][tid], red[3][tid]));
  __syncthreads();
  float sm[8];
#pragma unroll
  for (int q = 0; q < 8; q++) {
    float mm = row[q];
    L[0][q] = __expf(L[0][q] - mm);
    L[1][q] = __expf(L[1][q] - mm);
    L[2][q] = __expf(L[2][q] - mm);
    sm[q] = L[0][q] + L[1][q] + L[2][q];
  }
#pragma unroll
  for (int d = 1; d < 64; d <<= 1)
#pragma unroll
    for (int q = 0; q < 8; q++) sm[q] += __shfl_xor(sm[q], d, 64);
  if ((tid & 63) == 0)
    for (int q = 0; q < 8; q++) red[wv][q] = sm[q];
  __syncthreads();
  if (tid < 8) row[tid] = 1.f / (red[0][tid] + red[1][tid] + red[2][tid] + red[3][tid]);
  __syncthreads();
#pragma unroll
  for (int q = 0; q < 8; q++) {
    float r = row[q];
    float* ap = abuf + ((size_t)(q0 + q) * 12 + h) * NN + tid;
    ap[0] = L[0][q] * r; ap[256] = L[1][q] * r; ap[512] = L[2][q] * r;
  }
}

// ---------------- 6. o_pair[q][h][c] = sum_k a[q,h,k] z[q,k,c]  -> cat cols 576.. ----------------
__global__ __launch_bounds__(256) void opair_kernel(const float* z, const float* abuf, float* cat) {
  int q = blockIdx.x, tid = threadIdx.x;
  int c = tid & 127, h0 = tid >> 7;
  const float* zp = z + (size_t)q * NN * 128 + c;
  const float* ap = abuf + (size_t)q * 12 * NN;
  float acc[6] = {0, 0, 0, 0, 0, 0};
  for (int k4 = 0; k4 < NN; k4 += 4) {
    float4 av[6];
#pragma unroll
    for (int j = 0; j < 6; j++) av[j] = ld4(ap + (h0 + 2 * j) * NN + k4);
#pragma unroll
    for (int kk = 0; kk < 4; kk++) {
      float zv = zp[(size_t)(k4 + kk) * 128];
      const float* avf;
#pragma unroll
      for (int j = 0; j < 6; j++) {
        avf = (const float*)&av[j];
        acc[j] += zv * avf[kk];
      }
    }
  }
#pragma unroll
  for (int j = 0; j < 6; j++)
    cat[(size_t)q * CATD + 576 + (h0 + 2 * j) * 128 + c] = acc[j];
}

// ---------------- 7a. o + o_pt partials over k-chunks (split-K for occupancy) ----------------
__global__ __launch_bounds__(256) void ovpart_kernel(const float* proj, const float* vpts,
                                                     const float* abuf, float* pov) {
  int h = blockIdx.x, q0 = blockIdx.y * 32, kz = blockIdx.z;
  int tid = threadIdx.x;
  int qg = tid >> 3, jb = tid & 7;
  int q = q0 + qg;
  const float* ap = abuf + ((size_t)q * 12 + h) * NN + kz * 192;
  const float* vp = proj + (size_t)(kz * 192) * KALL + 384 + h * 16;
  const float* vpp = vpts + (size_t)(kz * 192) * 288 + h * 24;
  float acc[5] = {0, 0, 0, 0, 0};
  for (int k = 0; k < 192; k += 4) {
    float4 a4 = ld4(ap + k);
    const float af[4] = {a4.x, a4.y, a4.z, a4.w};
#pragma unroll
    for (int kk = 0; kk < 4; kk++) {
      float av = af[kk];
      size_t kr = k + kk;
      acc[0] += av * vp[kr * KALL + jb];
      acc[1] += av * vp[kr * KALL + jb + 8];
      acc[2] += av * vpp[kr * 288 + jb];
      acc[3] += av * vpp[kr * 288 + jb + 8];
      acc[4] += av * vpp[kr * 288 + jb + 16];
    }
  }
  float* o = pov + (((size_t)kz * 768 + q) * 12 + h) * 40;
  o[jb] = acc[0]; o[jb + 8] = acc[1];
  o[16 + jb] = acc[2]; o[16 + jb + 8] = acc[3]; o[16 + jb + 16] = acc[4];
}

// ---------------- 7b. reduce partials; o -> cat; inverse rigid + norm for o_pt ----------------
__global__ __launch_bounds__(256) void ovred_kernel(const float* pov, const float* rot,
                                                    const float* trans, float* cat) {
  int q = blockIdx.x, tid = threadIdx.x;
  const float* pq = pov + (size_t)q * 480;
  if (tid < 96) {
    int h = tid >> 3, p = tid & 7;
    float x = 0.f, y = 0.f, zz = 0.f;
#pragma unroll
    for (int j = 0; j < 4; j++) {
      const float* b = pq + (size_t)j * 768 * 480 + h * 40 + 16 + p * 3;
      x += b[0]; y += b[1]; zz += b[2];
    }
    const float* R = rot + q * 9;
    const float* T = trans + q * 3;
    float dx = x - T[0], dy = y - T[1], dz = zz - T[2];
    float lx = R[0] * dx + R[3] * dy + R[6] * dz;
    float ly = R[1] * dx + R[4] * dy + R[7] * dz;
    float lz = R[2] * dx + R[5] * dy + R[8] * dz;
    float nrm = sqrtf(lx * lx + ly * ly + lz * lz + 1e-8f);
    int hp = h * 8 + p;
    float* co = cat + (size_t)q * CATD;
    co[192 + hp] = lx; co[288 + hp] = ly; co[384 + hp] = lz; co[480 + hp] = nrm;
  } else {
    int i = tid - 96;
    int h = i >> 4, c = i & 15;
    float s = 0.f;
#pragma unroll
    for (int j = 0; j < 4; j++) s += pq[(size_t)j * 768 * 480 + h * 40 + c];
    cat[(size_t)q * CATD + h * 16 + c] = s;
    if (i < 32) {
      int i2 = i + 160;
      int h2 = i2 >> 4, c2 = i2 & 15;
      float s2 = 0.f;
#pragma unroll
      for (int j = 0; j < 4; j++) s2 += pq[(size_t)j * 768 * 480 + h2 * 40 + c2];
      cat[(size_t)q * CATD + h2 * 16 + c2] = s2;
    }
  }
}

// ---------------- 8a. out partials: split-K GEMM  cat[768x2112] @ wo[2112x384] ----------------
__global__ __launch_bounds__(256) void out_part_kernel(const float* cat, const float* wo,
                                                       float* part) {
  int q0 = blockIdx.x * 16, c0 = blockIdx.y * 64, k0 = blockIdx.z * 264;
  int tid = threadIdx.x;
  int q = q0 + (tid >> 4);
  int c = c0 + (tid & 15) * 4;
  const float* cp = cat + (size_t)q * CATD + k0;
  const float* wp = wo + (size_t)k0 * 384 + c;
  float4 acc = {0, 0, 0, 0};
#pragma unroll 8
  for (int k = 0; k < 264; k++) {
    float a = cp[k];
    float4 w4 = ld4(wp + (size_t)k * 384);
    acc.x += a * w4.x; acc.y += a * w4.y; acc.z += a * w4.z; acc.w += a * w4.w;
  }
  *(float4*)(part + ((size_t)blockIdx.z * 768 + q) * 384 + c) = acc;
}

// ---------------- 8b. out = sum_j part[j] + b_o ----------------
__global__ __launch_bounds__(256) void out_reduce_kernel(const float* part, const float* bo,
                                                         float* out) {
  int idx = blockIdx.x * 256 + threadIdx.x;
  int q = idx / 96, cg = idx - q * 96;
  int c = cg * 4;
  float4 acc = ld4(bo + c);
#pragma unroll
  for (int j = 0; j < 8; j++) {
    float4 p = ld4(part + ((size_t)j * 768 + q) * 384 + c);
    acc.x += p.x; acc.y += p.y; acc.z += p.z; acc.w += p.w;
  }
  *(float4*)(out + (size_t)q * 384 + c) = acc;
}

extern "C" void kernel_launch(void* const* d_in, const int* in_sizes, int n_in,
                              void* d_out, int out_size, void* d_ws, size_t ws_size,
                              hipStream_t stream) {
  const float* s     = (const float*)d_in[0];
  const float* z     = (const float*)d_in[1];
  const float* rot   = (const float*)d_in[2];
  const float* trans = (const float*)d_in[3];
  const float* mask  = (const float*)d_in[4];
  const float* wq    = (const float*)d_in[5];
  const float* bq    = (const float*)d_in[6];
  const float* wk    = (const float*)d_in[7];
  const float* bk    = (const float*)d_in[8];
  const float* wv    = (const float*)d_in[9];
  const float* bv    = (const float*)d_in[10];
  const float* wqp   = (const float*)d_in[11];
  const float* bqp   = (const float*)d_in[12];
  const float* wkp   = (const float*)d_in[13];
  const float* bkp   = (const float*)d_in[14];
  const float* wvp   = (const float*)d_in[15];
  const float* bvp   = (const float*)d_in[16];
  const float* wb    = (const float*)d_in[17];
  const float* bb    = (const float*)d_in[18];
  const float* hw    = (const float*)d_in[19];
  const float* wo    = (const float*)d_in[20];
  const float* bo    = (const float*)d_in[21];
  float* out = (float*)d_out;

  float* ws = (float*)d_ws;
  float* proj  = ws;                       // 768*1152
  float* Wall  = proj + 884736;            // 384*1152
  float* ball  = Wall + 442368;            // 1152
  float* qpts  = ball + 1152;              // 768*144
  float* kpts  = qpts + 110592;            // 768*144
  float* vpts  = kpts + 110592;            // 768*288
  float* q2    = vpts + 221184;            // 768*12
  float* k2    = q2 + 9216;                // 768*12
  float* abuf  = k2 + 9216;                // 768*12*768
  float* cat   = abuf + 7077888;           // 768*2112
  float* part  = cat + 1622016;            // 8*768*384
  float* wtr   = part + 2359296;           // 12*128
  float* pov   = wtr + 2048;               // 4*768*12*40

  pack_kernel<<<dim3((PACKN + 1536 + 255) / 256), 256, 0, stream>>>(
      wq, bq, wk, bk, wv, bv, wqp, bqp, wkp, bkp, wvp, bvp, wb, Wall, ball, wtr);
  proj_kernel<<<dim3(24, 18), 256, 0, stream>>>(s, Wall, ball, proj);
  points_kernel<<<dim3(768), 256, 0, stream>>>(proj, rot, trans, qpts, kpts, vpts, q2, k2);
  bias_kernel<<<dim3(768, 8), 256, 0, stream>>>(z, wtr, bb, abuf);
  softmax_kernel<<<dim3(96, 12), 256, 0, stream>>>(proj, qpts, kpts, q2, k2, mask, hw, abuf);
  opair_kernel<<<dim3(768), 256, 0, stream>>>(z, abuf, cat);
  ovpart_kernel<<<dim3(12, 24, 4), 256, 0, stream>>>(proj, vpts, abuf, pov);
  ovred_kernel<<<dim3(768), 256, 0, stream>>>(pov, rot, trans, cat);
  out_part_kernel<<<dim3(48, 6, 8), 256, 0, stream>>>(cat, wo, part);
  out_reduce_kernel<<<dim3(288), 256, 0, stream>>>(part, bo, out);
}

// Round 3
// 766.045 us; speedup vs baseline: 1.3945x; 1.1400x over previous
//
#include <hip/hip_runtime.h>
#include <math.h>

#define NN 768
#define KALL 1152     // 192*3 + 144*2 + 288
#define CATD 2112     // 192 + 3*96 + 96 + 1536
#define INF_ 100000.0f
#define PACKN (385 * KALL)

__device__ __forceinline__ float4 ld4(const float* p) { return *(const float4*)p; }

// quad reduce via DPP (VALU, no LDS pipe): sum over lanes {l, l^1, l^2, l^3}
__device__ __forceinline__ float qsum_dpp(float v) {
  v += __int_as_float(__builtin_amdgcn_mov_dpp(__float_as_int(v), 0xB1, 0xF, 0xF, true));  // quad_perm [1,0,3,2]
  v += __int_as_float(__builtin_amdgcn_mov_dpp(__float_as_int(v), 0x4E, 0xF, 0xF, true));  // quad_perm [2,3,0,1]
  return v;
}

// ---------------- 1. pack combined projection weights (q scaled by 0.25) + wtr ----------------
__global__ __launch_bounds__(256) void pack_kernel(
    const float* wq, const float* bq, const float* wk, const float* bk,
    const float* wv, const float* bv, const float* wqp, const float* bqp,
    const float* wkp, const float* bkp, const float* wvp, const float* bvp,
    const float* wbm, float* Wall, float* ball, float* wtr) {
  int idx = blockIdx.x * 256 + threadIdx.x;
  if (idx >= PACKN + 1536) return;
  if (idx >= PACKN) {
    // wtr[h*128 + c] = wb[c*12 + h]  (transposed pair-bias weights)
    int u = idx - PACKN;
    int h = u >> 7, c = u & 127;
    wtr[u] = wbm[c * 12 + h];
    return;
  }
  int kk = idx / KALL, u = idx - kk * KALL;
  const float *w, *b; int col, dim; float sc = 1.f;
  if (u < 192)      { w = wq;  b = bq;  col = u;       dim = 192; sc = 0.25f; }
  else if (u < 384) { w = wk;  b = bk;  col = u - 192; dim = 192; }
  else if (u < 576) { w = wv;  b = bv;  col = u - 384; dim = 192; }
  else if (u < 720) { w = wqp; b = bqp; col = u - 576; dim = 144; }
  else if (u < 864) { w = wkp; b = bkp; col = u - 720; dim = 144; }
  else              { w = wvp; b = bvp; col = u - 864; dim = 288; }
  if (kk < 384) Wall[kk * KALL + u] = sc * w[kk * dim + col];
  else          ball[u] = sc * b[col];
}

// ---------------- 2. proj = s @ Wall + ball   [768 x 1152] ----------------
__global__ __launch_bounds__(256) void proj_kernel(const float* s, const float* Wall,
                                                   const float* ball, float* proj) {
  int q0 = blockIdx.x * 32, c0 = blockIdx.y * 64;
  int tid = threadIdx.x;
  int qa = q0 + (tid >> 4) * 2, qb = qa + 1;
  int c = c0 + (tid & 15) * 4;
  const float* sa = s + qa * 384;
  const float* sb = s + qb * 384;
  const float* wp = Wall + c;
  float4 acc0 = {0, 0, 0, 0}, acc1 = {0, 0, 0, 0};
#pragma unroll 4
  for (int k = 0; k < 384; k++) {
    float4 w4 = ld4(wp + k * KALL);
    float a0 = sa[k], a1 = sb[k];
    acc0.x += a0 * w4.x; acc0.y += a0 * w4.y; acc0.z += a0 * w4.z; acc0.w += a0 * w4.w;
    acc1.x += a1 * w4.x; acc1.y += a1 * w4.y; acc1.z += a1 * w4.z; acc1.w += a1 * w4.w;
  }
  float4 b4 = ld4(ball + c);
  acc0.x += b4.x; acc0.y += b4.y; acc0.z += b4.z; acc0.w += b4.w;
  acc1.x += b4.x; acc1.y += b4.y; acc1.z += b4.z; acc1.w += b4.w;
  *(float4*)(proj + (size_t)qa * KALL + c) = acc0;
  *(float4*)(proj + (size_t)qb * KALL + c) = acc1;
}

// ---------------- 3. rigid-transform points + q2/k2 ----------------
__global__ __launch_bounds__(256) void points_kernel(const float* proj, const float* rot,
                                                     const float* trans, float* qpts, float* kpts,
                                                     float* vpts, float* q2, float* k2) {
  int n = blockIdx.x, tid = threadIdx.x;
  __shared__ float sq[12], sk[12];
  if (tid < 12) { sq[tid] = 0.f; sk[tid] = 0.f; }
  __syncthreads();
  if (tid < 192) {
    const float* R = rot + n * 9;
    const float* T = trans + n * 3;
    const float* pr = proj + (size_t)n * KALL;
    int base, P; float* outp; int h; bool isq = false, isk = false;
    if (tid < 48)      { h = tid >> 2; int p = tid & 3; base = 576 + h * 12; P = 4;
                         outp = qpts + n * 144 + h * 12 + p * 3; base += p; isq = true; }
    else if (tid < 96) { int i = tid - 48; h = i >> 2; int p = i & 3; base = 720 + h * 12; P = 4;
                         outp = kpts + n * 144 + h * 12 + p * 3; base += p; isk = true; }
    else               { int i = tid - 96; h = i >> 3; int p = i & 7; base = 864 + h * 24; P = 8;
                         outp = vpts + n * 288 + h * 24 + p * 3; base += p; }
    float l0 = pr[base], l1 = pr[base + P], l2 = pr[base + 2 * P];
    float g0 = R[0] * l0 + R[1] * l1 + R[2] * l2 + T[0];
    float g1 = R[3] * l0 + R[4] * l1 + R[5] * l2 + T[1];
    float g2 = R[6] * l0 + R[7] * l1 + R[8] * l2 + T[2];
    outp[0] = g0; outp[1] = g1; outp[2] = g2;
    float ns = g0 * g0 + g1 * g1 + g2 * g2;
    if (isq) atomicAdd(&sq[h], ns);
    else if (isk) atomicAdd(&sk[h], ns);
  }
  __syncthreads();
  if (tid < 12) { q2[n * 12 + tid] = sq[tid]; k2[n * 12 + tid] = sk[tid]; }
}

// ---------------- 4. bias[q][h][k] = z[q,k,:] . w_b[:,h] + b_b[h] ----------------
// Streaming z: 32-lane group owns a k-row, lane owns a c-quad; wave reads rows (k,k+1)
// as one contiguous 1KB burst. Weights k-invariant in VGPRs. Quad-reduce via DPP (VALU,
// zero DS-pipe) -> 8 quad-partials per row -> LDS -> coalesced dump.
__global__ __launch_bounds__(256, 4) void bias_kernel(const float* __restrict__ z,
                                                      const float* __restrict__ wtr,
                                                      const float* __restrict__ bb,
                                                      float* __restrict__ abuf) {
  int q = blockIdx.x, k0 = blockIdx.y * 96;
  int tid = threadIdx.x;
  int lane = tid & 63;
  int wv = tid >> 6;          // wave 0..3
  int grp = lane >> 5;        // row parity within wave
  int cl = lane & 31;         // c-quad index
  __shared__ float lsm[96 * 100];  // [row][quad*12 + sub*4 ...], padded stride 100

  // per-lane weights: w4[h] = wtr[h*128 + cl*4 .. +3]
  float4 w4[12];
#pragma unroll
  for (int h = 0; h < 12; h++) w4[h] = ld4(wtr + h * 128 + cl * 4);

  const float* zq = z + ((size_t)q * NN + k0) * 128;
  int rbase = wv * 24;
  int quad = cl >> 2, sub = cl & 3;
#pragma unroll 2
  for (int it = 0; it < 12; it++) {
    int rloc = rbase + it * 2 + grp;  // 0..95
    float4 z4 = ld4(zq + (size_t)rloc * 128 + cl * 4);
    float a[12];
#pragma unroll
    for (int h = 0; h < 12; h++)
      a[h] = z4.x * w4[h].x + z4.y * w4[h].y + z4.z * w4[h].z + z4.w * w4[h].w;
#pragma unroll
    for (int h = 0; h < 12; h++) a[h] = qsum_dpp(a[h]);
    // quad-sum now in all 4 lanes of each quad; lanes sub=0,1,2 write h-groups 0..3,4..7,8..11
    bool s1 = (sub == 1), s2 = (sub == 2);
    float vx = s1 ? a[4] : (s2 ? a[8]  : a[0]);
    float vy = s1 ? a[5] : (s2 ? a[9]  : a[1]);
    float vz = s1 ? a[6] : (s2 ? a[10] : a[2]);
    float vw = s1 ? a[7] : (s2 ? a[11] : a[3]);
    if (sub < 3) {
      float* p = lsm + rloc * 100 + quad * 12 + sub * 4;
      *(float4*)p = make_float4(vx, vy, vz, vw);
    }
  }
  __syncthreads();
  // dump: 96 rows x 12 h; sum 8 quad partials; coalesced global write
  for (int i = tid; i < 96 * 12; i += 256) {
    int h = i / 96, k = i - h * 96;
    const float* p = lsm + k * 100 + h;
    float ssum = bb[h];
#pragma unroll
    for (int g = 0; g < 8; g++) ssum += p[g * 12];
    abuf[((size_t)q * 12 + h) * NN + k0 + k] = ssum;
  }
}

// ---------------- 5. logits + softmax (in-place over abuf) ----------------
__global__ __launch_bounds__(256) void softmax_kernel(const float* proj, const float* qpts,
                                                      const float* kpts, const float* q2,
                                                      const float* k2, const float* mask,
                                                      const float* hw, float* abuf) {
  int q0 = blockIdx.x * 8, h = blockIdx.y;
  int tid = threadIdx.x;
  __shared__ float qw[8][16], qp[8][12], q2s[8], mq[8], red[4][8], row[8], pws;
  if (tid < 128) qw[tid >> 4][tid & 15] = proj[(size_t)(q0 + (tid >> 4)) * KALL + h * 16 + (tid & 15)];
  else if (tid < 224) { int i = tid - 128; qp[i / 12][i % 12] = qpts[(q0 + i / 12) * 144 + h * 12 + i % 12]; }
  else if (tid < 232) q2s[tid - 224] = q2[(q0 + tid - 224) * 12 + h];
  else if (tid < 240) mq[tid - 232] = mask[q0 + tid - 232];
  else if (tid == 240) {
    float x = hw[h];
    pws = 0.23570226039551584f * (fmaxf(x, 0.f) + log1pf(__expf(-fabsf(x))));
  }
  __syncthreads();

  float L[3][8];
#pragma unroll
  for (int i = 0; i < 3; i++) {
    int kk = i * 256 + tid;
    float kw[16], kp[12];
    const float* kwp = proj + (size_t)kk * KALL + 192 + h * 16;
    *(float4*)(kw) = ld4(kwp); *(float4*)(kw + 4) = ld4(kwp + 4);
    *(float4*)(kw + 8) = ld4(kwp + 8); *(float4*)(kw + 12) = ld4(kwp + 12);
    const float* kpp = kpts + (size_t)kk * 144 + h * 12;
    *(float4*)(kp) = ld4(kpp); *(float4*)(kp + 4) = ld4(kpp + 4); *(float4*)(kp + 8) = ld4(kpp + 8);
    float k2v = k2[kk * 12 + h];
    float mk = mask[kk];
#pragma unroll
    for (int q = 0; q < 8; q++) {
      float4 qa = *(const float4*)&qw[q][0];
      float4 qb = *(const float4*)&qw[q][4];
      float4 qc = *(const float4*)&qw[q][8];
      float4 qd = *(const float4*)&qw[q][12];
      float4 pa = *(const float4*)&qp[q][0];
      float4 pb = *(const float4*)&qp[q][4];
      float4 pc = *(const float4*)&qp[q][8];
      float d = qa.x * kw[0] + qa.y * kw[1] + qa.z * kw[2] + qa.w * kw[3]
              + qb.x * kw[4] + qb.y * kw[5] + qb.z * kw[6] + qb.w * kw[7]
              + qc.x * kw[8] + qc.y * kw[9] + qc.z * kw[10] + qc.w * kw[11]
              + qd.x * kw[12] + qd.y * kw[13] + qd.z * kw[14] + qd.w * kw[15];
      float dp = pa.x * kp[0] + pa.y * kp[1] + pa.z * kp[2] + pa.w * kp[3]
               + pb.x * kp[4] + pb.y * kp[5] + pb.z * kp[6] + pb.w * kp[7]
               + pc.x * kp[8] + pc.y * kp[9] + pc.z * kp[10] + pc.w * kp[11];
      float bias = abuf[((size_t)(q0 + q) * 12 + h) * NN + kk];
      float val = bias + d - 0.5f * pws * (q2s[q] + k2v - 2.f * dp) + INF_ * (mq[q] * mk - 1.f);
      L[i][q] = val * 0.5773502691896258f;
    }
  }
  float m[8];
#pragma unroll
  for (int q = 0; q < 8; q++) m[q] = fmaxf(fmaxf(L[0][q], L[1][q]), L[2][q]);
#pragma unroll
  for (int d = 1; d < 64; d <<= 1)
#pragma unroll
    for (int q = 0; q < 8; q++) m[q] = fmaxf(m[q], __shfl_xor(m[q], d, 64));
  int wv = tid >> 6;
  if ((tid & 63) == 0)
    for (int q = 0; q < 8; q++) red[wv][q] = m[q];
  __syncthreads();
  if (tid < 8) row[tid] = fmaxf(fmaxf(red[0][tid], red[1][tid]), fmaxf(red[2][tid], red[3][tid]));
  __syncthreads();
  float sm[8];
#pragma unroll
  for (int q = 0; q < 8; q++) {
    float mm = row[q];
    L[0][q] = __expf(L[0][q] - mm);
    L[1][q] = __expf(L[1][q] - mm);
    L[2][q] = __expf(L[2][q] - mm);
    sm[q] = L[0][q] + L[1][q] + L[2][q];
  }
#pragma unroll
  for (int d = 1; d < 64; d <<= 1)
#pragma unroll
    for (int q = 0; q < 8; q++) sm[q] += __shfl_xor(sm[q], d, 64);
  if ((tid & 63) == 0)
    for (int q = 0; q < 8; q++) red[wv][q] = sm[q];
  __syncthreads();
  if (tid < 8) row[tid] = 1.f / (red[0][tid] + red[1][tid] + red[2][tid] + red[3][tid]);
  __syncthreads();
#pragma unroll
  for (int q = 0; q < 8; q++) {
    float r = row[q];
    float* ap = abuf + ((size_t)(q0 + q) * 12 + h) * NN + tid;
    ap[0] = L[0][q] * r; ap[256] = L[1][q] * r; ap[512] = L[2][q] * r;
  }
}

// ---------------- 6. o_pair[q][h][c] = sum_k a[q,h,k] z[q,k,c]  -> cat cols 576.. ----------------
// Lane owns (c-quad, row-group): z read as half-wave-contiguous float4, a as broadcast float4,
// 48 register accumulators, cross-group LDS reduce (padded g-stride, conflict-free reads).
__global__ __launch_bounds__(256) void opair_kernel(const float* __restrict__ z,
                                                    const float* __restrict__ abuf,
                                                    float* __restrict__ cat) {
  int q = blockIdx.x, tid = threadIdx.x;
  int cq = tid & 31;   // c-quad: c = cq*4 .. cq*4+3
  int g  = tid >> 5;   // row group: rows g*96 .. g*96+95
  __shared__ float red[8 * 1540];  // g-stride 1540 = 12*128 + 4 pad
  const float* zp = z + ((size_t)q * NN + g * 96) * 128 + cq * 4;
  const float* ap = abuf + (size_t)q * 12 * NN + g * 96;
  float acc[12][4];
#pragma unroll
  for (int h = 0; h < 12; h++) { acc[h][0] = 0.f; acc[h][1] = 0.f; acc[h][2] = 0.f; acc[h][3] = 0.f; }
  for (int r = 0; r < 96; r += 4) {
    float4 z0 = ld4(zp + (size_t)(r + 0) * 128);
    float4 z1 = ld4(zp + (size_t)(r + 1) * 128);
    float4 z2 = ld4(zp + (size_t)(r + 2) * 128);
    float4 z3 = ld4(zp + (size_t)(r + 3) * 128);
#pragma unroll
    for (int h = 0; h < 12; h++) {
      float4 a4 = ld4(ap + h * NN + r);
      acc[h][0] += a4.x * z0.x + a4.y * z1.x + a4.z * z2.x + a4.w * z3.x;
      acc[h][1] += a4.x * z0.y + a4.y * z1.y + a4.z * z2.y + a4.w * z3.y;
      acc[h][2] += a4.x * z0.z + a4.y * z1.z + a4.z * z2.z + a4.w * z3.z;
      acc[h][3] += a4.x * z0.w + a4.y * z1.w + a4.z * z2.w + a4.w * z3.w;
    }
  }
#pragma unroll
  for (int h = 0; h < 12; h++)
    *(float4*)(red + g * 1540 + h * 128 + cq * 4) = *(float4*)acc[h];
  __syncthreads();
#pragma unroll
  for (int i = 0; i < 6; i++) {
    int idx = i * 256 + tid;   // = h*128 + c
    float ssum = 0.f;
#pragma unroll
    for (int gg = 0; gg < 8; gg++) ssum += red[gg * 1540 + idx];
    cat[(size_t)q * CATD + 576 + idx] = ssum;
  }
}

// ---------------- 7a. o + o_pt partials over k-chunks (split-K for occupancy) ----------------
__global__ __launch_bounds__(256) void ovpart_kernel(const float* proj, const float* vpts,
                                                     const float* abuf, float* pov) {
  int h = blockIdx.x, q0 = blockIdx.y * 32, kz = blockIdx.z;
  int tid = threadIdx.x;
  int qg = tid >> 3, jb = tid & 7;
  int q = q0 + qg;
  const float* ap = abuf + ((size_t)q * 12 + h) * NN + kz * 192;
  const float* vp = proj + (size_t)(kz * 192) * KALL + 384 + h * 16;
  const float* vpp = vpts + (size_t)(kz * 192) * 288 + h * 24;
  float acc[5] = {0, 0, 0, 0, 0};
  for (int k = 0; k < 192; k += 4) {
    float4 a4 = ld4(ap + k);
    const float af[4] = {a4.x, a4.y, a4.z, a4.w};
#pragma unroll
    for (int kk = 0; kk < 4; kk++) {
      float av = af[kk];
      size_t kr = k + kk;
      acc[0] += av * vp[kr * KALL + jb];
      acc[1] += av * vp[kr * KALL + jb + 8];
      acc[2] += av * vpp[kr * 288 + jb];
      acc[3] += av * vpp[kr * 288 + jb + 8];
      acc[4] += av * vpp[kr * 288 + jb + 16];
    }
  }
  float* o = pov + (((size_t)kz * 768 + q) * 12 + h) * 40;
  o[jb] = acc[0]; o[jb + 8] = acc[1];
  o[16 + jb] = acc[2]; o[16 + jb + 8] = acc[3]; o[16 + jb + 16] = acc[4];
}

// ---------------- 7b. reduce partials; o -> cat; inverse rigid + norm for o_pt ----------------
__global__ __launch_bounds__(256) void ovred_kernel(const float* pov, const float* rot,
                                                    const float* trans, float* cat) {
  int q = blockIdx.x, tid = threadIdx.x;
  const float* pq = pov + (size_t)q * 480;
  if (tid < 96) {
    int h = tid >> 3, p = tid & 7;
    float x = 0.f, y = 0.f, zz = 0.f;
#pragma unroll
    for (int j = 0; j < 4; j++) {
      const float* b = pq + (size_t)j * 768 * 480 + h * 40 + 16 + p * 3;
      x += b[0]; y += b[1]; zz += b[2];
    }
    const float* R = rot + q * 9;
    const float* T = trans + q * 3;
    float dx = x - T[0], dy = y - T[1], dz = zz - T[2];
    float lx = R[0] * dx + R[3] * dy + R[6] * dz;
    float ly = R[1] * dx + R[4] * dy + R[7] * dz;
    float lz = R[2] * dx + R[5] * dy + R[8] * dz;
    float nrm = sqrtf(lx * lx + ly * ly + lz * lz + 1e-8f);
    int hp = h * 8 + p;
    float* co = cat + (size_t)q * CATD;
    co[192 + hp] = lx; co[288 + hp] = ly; co[384 + hp] = lz; co[480 + hp] = nrm;
  } else {
    int i = tid - 96;
    int h = i >> 4, c = i & 15;
    float s = 0.f;
#pragma unroll
    for (int j = 0; j < 4; j++) s += pq[(size_t)j * 768 * 480 + h * 40 + c];
    cat[(size_t)q * CATD + h * 16 + c] = s;
    if (i < 32) {
      int i2 = i + 160;
      int h2 = i2 >> 4, c2 = i2 & 15;
      float s2 = 0.f;
#pragma unroll
      for (int j = 0; j < 4; j++) s2 += pq[(size_t)j * 768 * 480 + h2 * 40 + c2];
      cat[(size_t)q * CATD + h2 * 16 + c2] = s2;
    }
  }
}

// ---------------- 8a. out partials: split-K GEMM  cat[768x2112] @ wo[2112x384] ----------------
__global__ __launch_bounds__(256) void out_part_kernel(const float* cat, const float* wo,
                                                       float* part) {
  int q0 = blockIdx.x * 16, c0 = blockIdx.y * 64, k0 = blockIdx.z * 264;
  int tid = threadIdx.x;
  int q = q0 + (tid >> 4);
  int c = c0 + (tid & 15) * 4;
  const float* cp = cat + (size_t)q * CATD + k0;
  const float* wp = wo + (size_t)k0 * 384 + c;
  float4 acc = {0, 0, 0, 0};
#pragma unroll 8
  for (int k = 0; k < 264; k++) {
    float a = cp[k];
    float4 w4 = ld4(wp + (size_t)k * 384);
    acc.x += a * w4.x; acc.y += a * w4.y; acc.z += a * w4.z; acc.w += a * w4.w;
  }
  *(float4*)(part + ((size_t)blockIdx.z * 768 + q) * 384 + c) = acc;
}

// ---------------- 8b. out = sum_j part[j] + b_o ----------------
__global__ __launch_bounds__(256) void out_reduce_kernel(const float* part, const float* bo,
                                                         float* out) {
  int idx = blockIdx.x * 256 + threadIdx.x;
  int q = idx / 96, cg = idx - q * 96;
  int c = cg * 4;
  float4 acc = ld4(bo + c);
#pragma unroll
  for (int j = 0; j < 8; j++) {
    float4 p = ld4(part + ((size_t)j * 768 + q) * 384 + c);
    acc.x += p.x; acc.y += p.y; acc.z += p.z; acc.w += p.w;
  }
  *(float4*)(out + (size_t)q * 384 + c) = acc;
}

extern "C" void kernel_launch(void* const* d_in, const int* in_sizes, int n_in,
                              void* d_out, int out_size, void* d_ws, size_t ws_size,
                              hipStream_t stream) {
  const float* s     = (const float*)d_in[0];
  const float* z     = (const float*)d_in[1];
  const float* rot   = (const float*)d_in[2];
  const float* trans = (const float*)d_in[3];
  const float* mask  = (const float*)d_in[4];
  const float* wq    = (const float*)d_in[5];
  const float* bq    = (const float*)d_in[6];
  const float* wk    = (const float*)d_in[7];
  const float* bk    = (const float*)d_in[8];
  const float* wv    = (const float*)d_in[9];
  const float* bv    = (const float*)d_in[10];
  const float* wqp   = (const float*)d_in[11];
  const float* bqp   = (const float*)d_in[12];
  const float* wkp   = (const float*)d_in[13];
  const float* bkp   = (const float*)d_in[14];
  const float* wvp   = (const float*)d_in[15];
  const float* bvp   = (const float*)d_in[16];
  const float* wb    = (const float*)d_in[17];
  const float* bb    = (const float*)d_in[18];
  const float* hw    = (const float*)d_in[19];
  const float* wo    = (const float*)d_in[20];
  const float* bo    = (const float*)d_in[21];
  float* out = (float*)d_out;

  float* ws = (float*)d_ws;
  float* proj  = ws;                       // 768*1152
  float* Wall  = proj + 884736;            // 384*1152
  float* ball  = Wall + 442368;            // 1152
  float* qpts  = ball + 1152;              // 768*144
  float* kpts  = qpts + 110592;            // 768*144
  float* vpts  = kpts + 110592;            // 768*288
  float* q2    = vpts + 221184;            // 768*12
  float* k2    = q2 + 9216;                // 768*12
  float* abuf  = k2 + 9216;                // 768*12*768
  float* cat   = abuf + 7077888;           // 768*2112
  float* part  = cat + 1622016;            // 8*768*384
  float* wtr   = part + 2359296;           // 12*128
  float* pov   = wtr + 2048;               // 4*768*12*40

  pack_kernel<<<dim3((PACKN + 1536 + 255) / 256), 256, 0, stream>>>(
      wq, bq, wk, bk, wv, bv, wqp, bqp, wkp, bkp, wvp, bvp, wb, Wall, ball, wtr);
  proj_kernel<<<dim3(24, 18), 256, 0, stream>>>(s, Wall, ball, proj);
  points_kernel<<<dim3(768), 256, 0, stream>>>(proj, rot, trans, qpts, kpts, vpts, q2, k2);
  bias_kernel<<<dim3(768, 8), 256, 0, stream>>>(z, wtr, bb, abuf);
  softmax_kernel<<<dim3(96, 12), 256, 0, stream>>>(proj, qpts, kpts, q2, k2, mask, hw, abuf);
  opair_kernel<<<dim3(768), 256, 0, stream>>>(z, abuf, cat);
  ovpart_kernel<<<dim3(12, 24, 4), 256, 0, stream>>>(proj, vpts, abuf, pov);
  ovred_kernel<<<dim3(768), 256, 0, stream>>>(pov, rot, trans, cat);
  out_part_kernel<<<dim3(48, 6, 8), 256, 0, stream>>>(cat, wo, part);
  out_reduce_kernel<<<dim3(288), 256, 0, stream>>>(part, bo, out);
}